// Round 3
// baseline (487.607 us; speedup 1.0000x reference)
//
#include <hip/hip_runtime.h>
#include <hip/hip_bf16.h>

#define N_NODES 8192
#define EMB 256
#define NHID 64
#define LOG2E 1.44269504088896340736f
#define PACK_BLOCKS 2048
#define K1_BLOCKS 2048  // N_NODES/4

typedef __attribute__((ext_vector_type(8))) short bf16x8;
typedef __attribute__((ext_vector_type(4))) float f32x4;

static __device__ __forceinline__ short f2bf(float f) {
  __hip_bfloat16 h = __float2bfloat16(f);  // round-to-nearest-even
  return *reinterpret_cast<short*>(&h);
}

// fast bf16 round (half-up in magnitude) — used on nonnegative attention
// weights where ties-away vs ties-even is noise.
static __device__ __forceinline__ short f2bf_fast(float f) {
  unsigned u = __builtin_bit_cast(unsigned, f);
  return (short)((u + 0x8000u) >> 16);
}

// Fused kernel 0+1.
//  blocks [0, PACK_BLOCKS): pack adj (int32 {0,1}) into a bitmask, reading
//    adj with long per-lane sequential runs (fill-shaped, DRAM-page friendly).
//  blocks [PACK_BLOCKS, +K1_BLOCKS): h = input @ W (one wave per row),
//    writes hT[d][row] bf16 + log2e-scaled s_src/s_dst.
__global__ __launch_bounds__(256) void gat_k01(
    const int* __restrict__ adj, unsigned* __restrict__ mask,
    const float* __restrict__ in, const float* __restrict__ W,
    const float* __restrict__ a, short* __restrict__ hT,
    float* __restrict__ ssrc, float* __restrict__ sdst) {
  if (blockIdx.x < PACK_BLOCKS) {
    const int nthreads = PACK_BLOCKS * 256;
    const int nchunks = (N_NODES * N_NODES) / 32;
    int tid = blockIdx.x * 256 + threadIdx.x;
    for (int c = tid; c < nchunks; c += nthreads) {
      const int4* p = reinterpret_cast<const int4*>(adj) + (size_t)c * 8;
      unsigned m = 0;
#pragma unroll
      for (int j = 0; j < 8; ++j) {
        int4 v = p[j];
        m |= (unsigned)(v.x & 1) << (j * 4 + 0);
        m |= (unsigned)(v.y & 1) << (j * 4 + 1);
        m |= (unsigned)(v.z & 1) << (j * 4 + 2);
        m |= (unsigned)(v.w & 1) << (j * 4 + 3);
      }
      mask[c] = m;
    }
    return;
  }
  int wave = threadIdx.x >> 6, lane = threadIdx.x & 63;
  int row = (blockIdx.x - PACK_BLOCKS) * 4 + wave;
  int d = lane;
  const float4* in4 = reinterpret_cast<const float4*>(in + (size_t)row * EMB);
  float acc = 0.f;
#pragma unroll 4
  for (int k4 = 0; k4 < EMB / 4; ++k4) {
    float4 x = in4[k4];
    int k = k4 * 4;
    acc = fmaf(x.x, W[(k + 0) * NHID + d], acc);
    acc = fmaf(x.y, W[(k + 1) * NHID + d], acc);
    acc = fmaf(x.z, W[(k + 2) * NHID + d], acc);
    acc = fmaf(x.w, W[(k + 3) * NHID + d], acc);
  }
  hT[(size_t)d * N_NODES + row] = f2bf(acc);
  float p1 = acc * a[d];
  float p2 = acc * a[NHID + d];
#pragma unroll
  for (int off = 32; off > 0; off >>= 1) {
    p1 += __shfl_xor(p1, off);
    p2 += __shfl_xor(p2, off);
  }
  if (lane == 0) {
    ssrc[row] = p1 * LOG2E;
    sdst[row] = p2 * LOG2E;
  }
}

// Kernel 2: fused masked-exp + P@h via bf16 MFMA, single pass over the
// bitmask (L2/L3-resident, 8 MB). Grid = 128 row-blocks x nsplit col splits.
// 4 waves/block, each wave owns 16 rows. No LDS; adj HBM traffic eliminated.
__global__ __launch_bounds__(256, 4) void gat_k2(
    const unsigned* __restrict__ mask, const short* __restrict__ hT,
    const float* __restrict__ ssrc, const float* __restrict__ sdst,
    float* __restrict__ pacc, float* __restrict__ pz,
    int nsplit, int colsPer) {
  int rb = blockIdx.x / nsplit;
  int split = blockIdx.x % nsplit;
  int wv = threadIdx.x >> 6, lane = threadIdx.x & 63;
  int lrow = lane & 15, kg = lane >> 4;
  int r0 = rb * 64 + wv * 16;
  int row = r0 + lrow;
  float s_i = ssrc[row];
  // mask row = 256 dwords; this split's slice = colsPer/32 dwords
  const unsigned* mrow = mask + (size_t)row * (N_NODES / 32) + split * (colsPer / 32);
  const short* hrow0 = hT + (size_t)(0 * 16 + lrow) * N_NODES;
  const short* hrow1 = hT + (size_t)(1 * 16 + lrow) * N_NODES;
  const short* hrow2 = hT + (size_t)(2 * 16 + lrow) * N_NODES;
  const short* hrow3 = hT + (size_t)(3 * 16 + lrow) * N_NODES;
  f32x4 acc0 = {0.f, 0.f, 0.f, 0.f};
  f32x4 acc1 = acc0, acc2 = acc0, acc3 = acc0;
  float zacc = 0.f;
  int jbase = split * colsPer + kg * 8;  // this lane's k-offset
  int nkt = colsPer >> 5;                // 32 cols per K-tile
  int kgsh = kg * 8;

  // 1-deep software prefetch of all per-tile streams
  unsigned mcur = mrow[0];
  float4 t0 = *reinterpret_cast<const float4*>(sdst + jbase);
  float4 t1 = *reinterpret_cast<const float4*>(sdst + jbase + 4);
  bf16x8 b0 = *reinterpret_cast<const bf16x8*>(hrow0 + jbase);
  bf16x8 b1 = *reinterpret_cast<const bf16x8*>(hrow1 + jbase);
  bf16x8 b2 = *reinterpret_cast<const bf16x8*>(hrow2 + jbase);
  bf16x8 b3 = *reinterpret_cast<const bf16x8*>(hrow3 + jbase);

  for (int kt = 0; kt < nkt; ++kt) {
    int ktn = (kt + 1 < nkt) ? kt + 1 : 0;
    int jn = jbase + ktn * 32;
    unsigned mnext = mrow[ktn];
    float4 nt0 = *reinterpret_cast<const float4*>(sdst + jn);
    float4 nt1 = *reinterpret_cast<const float4*>(sdst + jn + 4);
    bf16x8 nb0 = *reinterpret_cast<const bf16x8*>(hrow0 + jn);
    bf16x8 nb1 = *reinterpret_cast<const bf16x8*>(hrow1 + jn);
    bf16x8 nb2 = *reinterpret_cast<const bf16x8*>(hrow2 + jn);
    bf16x8 nb3 = *reinterpret_cast<const bf16x8*>(hrow3 + jn);

    float tv[8] = {t0.x, t0.y, t0.z, t0.w, t1.x, t1.y, t1.z, t1.w};
    unsigned mb = (mcur >> kgsh) & 0xffu;  // this kg's 8 mask bits
    bf16x8 af;
#pragma unroll
    for (int e = 0; e < 8; ++e) {
      float x = s_i + tv[e];                   // log2-domain score
      float lk = fmaxf(x, 0.2f * x);           // leakyrelu (alpha<1)
      float ev = __builtin_amdgcn_exp2f(lk);   // exp(leaky(s+t))
      float w = (mb & (1u << e)) ? ev : 0.f;   // mask
      zacc += w;
      af[e] = f2bf_fast(w);
    }
    acc0 = __builtin_amdgcn_mfma_f32_16x16x32_bf16(af, b0, acc0, 0, 0, 0);
    acc1 = __builtin_amdgcn_mfma_f32_16x16x32_bf16(af, b1, acc1, 0, 0, 0);
    acc2 = __builtin_amdgcn_mfma_f32_16x16x32_bf16(af, b2, acc2, 0, 0, 0);
    acc3 = __builtin_amdgcn_mfma_f32_16x16x32_bf16(af, b3, acc3, 0, 0, 0);

    mcur = mnext; t0 = nt0; t1 = nt1;
    b0 = nb0; b1 = nb1; b2 = nb2; b3 = nb3;
  }

  // Z: A-layout row = lane&15; full sum over lanes {r, r+16, r+32, r+48}
  float z = zacc;
  z += __shfl_xor(z, 16);
  z += __shfl_xor(z, 32);
  if (lane < 16) pz[(size_t)split * N_NODES + r0 + lane] = z;

  // C/D layout: row = (lane>>4)*4 + reg, col = lane&15
  float* pa = pacc + (size_t)split * (N_NODES * NHID);
#pragma unroll
  for (int reg = 0; reg < 4; ++reg) {
    int orow = r0 + kg * 4 + reg;
    pa[(size_t)orow * NHID + 0 * 16 + lrow] = acc0[reg];
    pa[(size_t)orow * NHID + 1 * 16 + lrow] = acc1[reg];
    pa[(size_t)orow * NHID + 2 * 16 + lrow] = acc2[reg];
    pa[(size_t)orow * NHID + 3 * 16 + lrow] = acc3[reg];
  }
}

// Kernel 3: combine split partials and normalize.
__global__ __launch_bounds__(256) void gat_k3(
    const float* __restrict__ pacc, const float* __restrict__ pz,
    float* __restrict__ out, int nsplit) {
  int idx = blockIdx.x * 256 + threadIdx.x;
  int row = idx >> 6;
  float num = 0.f, den = 0.f;
  for (int s = 0; s < nsplit; ++s) {
    num += pacc[(size_t)s * (N_NODES * NHID) + idx];
    den += pz[(size_t)s * N_NODES + row];
  }
  out[idx] = num / den;
}

extern "C" void kernel_launch(void* const* d_in, const int* in_sizes, int n_in,
                              void* d_out, int out_size, void* d_ws, size_t ws_size,
                              hipStream_t stream) {
  (void)in_sizes; (void)n_in; (void)out_size;
  const float* in = (const float*)d_in[0];
  const int* adj = (const int*)d_in[1];
  const float* W = (const float*)d_in[2];
  const float* a = (const float*)d_in[3];
  float* out = (float*)d_out;

  // ws: hT (1 MB) | ssrc (32K) | sdst (32K) | pz (S*32K) | pacc (S*2 MB) | mask (8 MB)
  int S = 8;
  while (S > 1 &&
         (size_t)1114112 + (size_t)S * 2129920 + (size_t)8388608 > ws_size)
    S >>= 1;
  int colsPer = N_NODES / S;

  char* w = (char*)d_ws;
  short* hT = (short*)w;
  float* ssrc = (float*)(w + (1u << 20));
  float* sdst = ssrc + N_NODES;
  float* pz = sdst + N_NODES;
  float* pacc = pz + (size_t)S * N_NODES;
  unsigned* mask = (unsigned*)(pacc + (size_t)S * (N_NODES * NHID));

  gat_k01<<<PACK_BLOCKS + K1_BLOCKS, 256, 0, stream>>>(adj, mask, in, W, a, hT,
                                                       ssrc, sdst);
  gat_k2<<<(N_NODES / 64) * S, 256, 0, stream>>>(mask, hT, ssrc, sdst, pacc,
                                                 pz, S, colsPer);
  gat_k3<<<(N_NODES * NHID) / 256, 256, 0, stream>>>(pacc, pz, out, S);
}

// Round 4
// 472.293 us; speedup vs baseline: 1.0324x; 1.0324x over previous
//
#include <hip/hip_runtime.h>
#include <hip/hip_bf16.h>

#define N_NODES 8192
#define EMB 256
#define NHID 64
#define LOG2E 1.44269504088896340736f
#define S_SPLIT 8
#define COLS_PER 1024  // N_NODES / S_SPLIT
#define NKT 32         // COLS_PER / 32

typedef __attribute__((ext_vector_type(8))) short bf16x8;
typedef __attribute__((ext_vector_type(4))) float f32x4;

static __device__ __forceinline__ short f2bf(float f) {
  __hip_bfloat16 h = __float2bfloat16(f);  // round-to-nearest-even
  return *reinterpret_cast<short*>(&h);
}

// fast bf16 round (half-up in magnitude) — used on nonnegative attention
// weights where ties-away vs ties-even rounding is noise.
static __device__ __forceinline__ short f2bf_fast(float f) {
  unsigned u = __builtin_bit_cast(unsigned, f);
  return (short)((u + 0x8000u) >> 16);
}

// Kernel 1: h = input @ W. One wave per row (lane = d).
// Writes hT[d][row] (bf16, transposed so k2's B-fragments are contiguous),
// and s_src/s_dst pre-scaled by log2(e).
__global__ __launch_bounds__(256) void gat_k1(
    const float* __restrict__ in, const float* __restrict__ W,
    const float* __restrict__ a, short* __restrict__ hT,
    float* __restrict__ ssrc, float* __restrict__ sdst) {
  int wave = threadIdx.x >> 6, lane = threadIdx.x & 63;
  int row = blockIdx.x * 4 + wave;
  int d = lane;
  const float4* in4 = reinterpret_cast<const float4*>(in + (size_t)row * EMB);
  float acc = 0.f;
#pragma unroll 4
  for (int k4 = 0; k4 < EMB / 4; ++k4) {
    float4 x = in4[k4];
    int k = k4 * 4;
    acc = fmaf(x.x, W[(k + 0) * NHID + d], acc);
    acc = fmaf(x.y, W[(k + 1) * NHID + d], acc);
    acc = fmaf(x.z, W[(k + 2) * NHID + d], acc);
    acc = fmaf(x.w, W[(k + 3) * NHID + d], acc);
  }
  hT[(size_t)d * N_NODES + row] = f2bf(acc);
  float p1 = acc * a[d];
  float p2 = acc * a[NHID + d];
#pragma unroll
  for (int off = 32; off > 0; off >>= 1) {
    p1 += __shfl_xor(p1, off);
    p2 += __shfl_xor(p2, off);
  }
  if (lane == 0) {
    ssrc[row] = p1 * LOG2E;
    sdst[row] = p2 * LOG2E;
  }
}

// Kernel 2: fused masked-exp + P@h via bf16 MFMA, single pass over adj.
// Grid = 128 row-blocks x 8 col splits. 4 waves/block, each wave owns 16 rows.
// Register-slimmed (~105 VGPR target, no spill at the 128 cap):
//   adj (the only HBM stream, ~900cy latency): 2-deep prefetch ring
//   sdst (L1/L2-resident): 1-deep ring
//   hT (L2-resident): no ring; loads issue ~160cy before their MFMAs
__global__ __launch_bounds__(256, 4) void gat_k2(
    const int* __restrict__ adj, const short* __restrict__ hT,
    const float* __restrict__ ssrc, const float* __restrict__ sdst,
    float* __restrict__ pacc, float* __restrict__ pz) {
  int rb = blockIdx.x / S_SPLIT;
  int split = blockIdx.x % S_SPLIT;
  int wv = threadIdx.x >> 6, lane = threadIdx.x & 63;
  int lrow = lane & 15, kg = lane >> 4;
  int r0 = rb * 64 + wv * 16;
  int row = r0 + lrow;
  float s_i = ssrc[row];
  const int* adjr = adj + (size_t)row * N_NODES;
  const short* h0 = hT + (size_t)(0 * 16 + lrow) * N_NODES;
  const short* h1 = hT + (size_t)(1 * 16 + lrow) * N_NODES;
  const short* h2 = hT + (size_t)(2 * 16 + lrow) * N_NODES;
  const short* h3 = hT + (size_t)(3 * 16 + lrow) * N_NODES;
  f32x4 acc0 = {0.f, 0.f, 0.f, 0.f};
  f32x4 acc1 = acc0, acc2 = acc0, acc3 = acc0;
  float zacc = 0.f;
  int jbase = split * COLS_PER + kg * 8;  // this lane's k-offset

  // adj ring: tiles kt (A0/B0) and kt+1 (A1/B1); sdst ring: tile kt
  int4 aA0 = *reinterpret_cast<const int4*>(adjr + jbase);
  int4 aB0 = *reinterpret_cast<const int4*>(adjr + jbase + 4);
  int4 aA1 = *reinterpret_cast<const int4*>(adjr + jbase + 32);
  int4 aB1 = *reinterpret_cast<const int4*>(adjr + jbase + 36);
  float4 tA = *reinterpret_cast<const float4*>(sdst + jbase);
  float4 tB = *reinterpret_cast<const float4*>(sdst + jbase + 4);

#pragma unroll 2
  for (int kt = 0; kt < NKT; ++kt) {
    int jb = jbase + kt * 32;
    int j2 = jbase + ((kt + 2) & (NKT - 1)) * 32;
    int j1 = jbase + ((kt + 1) & (NKT - 1)) * 32;
    // issue the long-latency streams first
    int4 nA = *reinterpret_cast<const int4*>(adjr + j2);
    int4 nB = *reinterpret_cast<const int4*>(adjr + j2 + 4);
    float4 ntA = *reinterpret_cast<const float4*>(sdst + j1);
    float4 ntB = *reinterpret_cast<const float4*>(sdst + j1 + 4);
    bf16x8 b0 = *reinterpret_cast<const bf16x8*>(h0 + jb);
    bf16x8 b1 = *reinterpret_cast<const bf16x8*>(h1 + jb);
    bf16x8 b2 = *reinterpret_cast<const bf16x8*>(h2 + jb);
    bf16x8 b3 = *reinterpret_cast<const bf16x8*>(h3 + jb);

    float tv[8] = {tA.x, tA.y, tA.z, tA.w, tB.x, tB.y, tB.z, tB.w};
    int av[8] = {aA0.x, aA0.y, aA0.z, aA0.w, aB0.x, aB0.y, aB0.z, aB0.w};
    bf16x8 af;
#pragma unroll
    for (int e = 0; e < 8; ++e) {
      float x = s_i + tv[e];                   // log2-domain score
      float lk = fmaxf(x, 0.2f * x);           // leakyrelu (alpha<1)
      float ev = __builtin_amdgcn_exp2f(lk);   // exp(leaky(s+t))
      float w = (av[e] != 0) ? ev : 0.f;       // mask
      zacc += w;
      af[e] = f2bf_fast(w);
    }
    acc0 = __builtin_amdgcn_mfma_f32_16x16x32_bf16(af, b0, acc0, 0, 0, 0);
    acc1 = __builtin_amdgcn_mfma_f32_16x16x32_bf16(af, b1, acc1, 0, 0, 0);
    acc2 = __builtin_amdgcn_mfma_f32_16x16x32_bf16(af, b2, acc2, 0, 0, 0);
    acc3 = __builtin_amdgcn_mfma_f32_16x16x32_bf16(af, b3, acc3, 0, 0, 0);

    aA0 = aA1; aB0 = aB1; aA1 = nA; aB1 = nB;
    tA = ntA; tB = ntB;
  }

  // Z: A-layout row = lane&15; full sum over lanes {r, r+16, r+32, r+48}
  float z = zacc;
  z += __shfl_xor(z, 16);
  z += __shfl_xor(z, 32);
  if (lane < 16) pz[(size_t)split * N_NODES + r0 + lane] = z;

  // C/D layout: row = (lane>>4)*4 + reg, col = lane&15
  float* pa = pacc + (size_t)split * (N_NODES * NHID);
#pragma unroll
  for (int reg = 0; reg < 4; ++reg) {
    int orow = r0 + kg * 4 + reg;
    pa[(size_t)orow * NHID + 0 * 16 + lrow] = acc0[reg];
    pa[(size_t)orow * NHID + 1 * 16 + lrow] = acc1[reg];
    pa[(size_t)orow * NHID + 2 * 16 + lrow] = acc2[reg];
    pa[(size_t)orow * NHID + 3 * 16 + lrow] = acc3[reg];
  }
}

// Kernel 3: combine split partials and normalize.
__global__ __launch_bounds__(256) void gat_k3(
    const float* __restrict__ pacc, const float* __restrict__ pz,
    float* __restrict__ out) {
  int idx = blockIdx.x * 256 + threadIdx.x;
  int row = idx >> 6;
  float num = 0.f, den = 0.f;
#pragma unroll
  for (int s = 0; s < S_SPLIT; ++s) {
    num += pacc[(size_t)s * (N_NODES * NHID) + idx];
    den += pz[(size_t)s * N_NODES + row];
  }
  out[idx] = num / den;
}

extern "C" void kernel_launch(void* const* d_in, const int* in_sizes, int n_in,
                              void* d_out, int out_size, void* d_ws, size_t ws_size,
                              hipStream_t stream) {
  (void)in_sizes; (void)n_in; (void)out_size; (void)ws_size;
  const float* in = (const float*)d_in[0];
  const int* adj = (const int*)d_in[1];
  const float* W = (const float*)d_in[2];
  const float* a = (const float*)d_in[3];
  float* out = (float*)d_out;

  // ws: hT (1 MB) | ssrc (32K) | sdst (32K) | pz (8*32K) | pacc (8*2 MB)
  char* w = (char*)d_ws;
  short* hT = (short*)w;
  float* ssrc = (float*)(w + (1u << 20));
  float* sdst = ssrc + N_NODES;
  float* pz = sdst + N_NODES;
  float* pacc = pz + (size_t)S_SPLIT * N_NODES;

  gat_k1<<<N_NODES / 4, 256, 0, stream>>>(in, W, a, hT, ssrc, sdst);
  gat_k2<<<(N_NODES / 64) * S_SPLIT, 256, 0, stream>>>(adj, hT, ssrc, sdst,
                                                       pacc, pz);
  gat_k3<<<(N_NODES * NHID) / 256, 256, 0, stream>>>(pacc, pz, out);
}

// Round 5
// 448.978 us; speedup vs baseline: 1.0860x; 1.0519x over previous
//
#include <hip/hip_runtime.h>
#include <hip/hip_bf16.h>

#define N_NODES 8192
#define EMB 256
#define NHID 64
#define LOG2E 1.44269504088896340736f
#define S_SPLIT 32
#define COLS 256       // cols per block = N_NODES / S_SPLIT
#define NKT 8          // K-tiles per block = COLS / 32
#define HROWB 264      // padded LDS row stride in shorts (528 B: +16 B pad)

typedef __attribute__((ext_vector_type(8))) short bf16x8;
typedef __attribute__((ext_vector_type(4))) float f32x4;

static __device__ __forceinline__ short f2bf(float f) {
  __hip_bfloat16 h = __float2bfloat16(f);  // round-to-nearest-even
  return *reinterpret_cast<short*>(&h);
}

// fast bf16 round (half-up in magnitude) — used on nonnegative attention
// weights where ties-away vs ties-even rounding is noise.
static __device__ __forceinline__ short f2bf_fast(float f) {
  unsigned u = __builtin_bit_cast(unsigned, f);
  return (short)((u + 0x8000u) >> 16);
}

// Kernel 1: h = input @ W. One wave per row (lane = d).
// Writes hT[d][row] (bf16, transposed) + log2e-scaled s_src/s_dst.
__global__ __launch_bounds__(256) void gat_k1(
    const float* __restrict__ in, const float* __restrict__ W,
    const float* __restrict__ a, short* __restrict__ hT,
    float* __restrict__ ssrc, float* __restrict__ sdst) {
  int wave = threadIdx.x >> 6, lane = threadIdx.x & 63;
  int row = blockIdx.x * 4 + wave;
  int d = lane;
  const float4* in4 = reinterpret_cast<const float4*>(in + (size_t)row * EMB);
  float acc = 0.f;
#pragma unroll 4
  for (int k4 = 0; k4 < EMB / 4; ++k4) {
    float4 x = in4[k4];
    int k = k4 * 4;
    acc = fmaf(x.x, W[(k + 0) * NHID + d], acc);
    acc = fmaf(x.y, W[(k + 1) * NHID + d], acc);
    acc = fmaf(x.z, W[(k + 2) * NHID + d], acc);
    acc = fmaf(x.w, W[(k + 3) * NHID + d], acc);
  }
  hT[(size_t)d * N_NODES + row] = f2bf(acc);
  float p1 = acc * a[d];
  float p2 = acc * a[NHID + d];
#pragma unroll
  for (int off = 32; off > 0; off >>= 1) {
    p1 += __shfl_xor(p1, off);
    p2 += __shfl_xor(p2, off);
  }
  if (lane == 0) {
    ssrc[row] = p1 * LOG2E;
    sdst[row] = p2 * LOG2E;
  }
}

// Kernel 2: fused masked-exp + P@h via bf16 MFMA.
// Block = 64 rows x 256 cols. hT slice + sdst slice staged in LDS ONCE;
// the K-loop's only global stream is adj (3-deep register ring), so
// FIFO-vmcnt gives ~3 iterations of adj latency tolerance.
__global__ __launch_bounds__(256, 4) void gat_k2(
    const int* __restrict__ adj, const short* __restrict__ hT,
    const float* __restrict__ ssrc, const float* __restrict__ sdst,
    float* __restrict__ pacc, float* __restrict__ pz) {
  __shared__ short hlds[64 * HROWB];  // 33792 B, padded rows
  __shared__ float tlds[COLS];        // 1 KB

  int split = blockIdx.x >> 7;        // blocks sharing split share hT slice
  int rb = blockIdx.x & 127;
  int tid = threadIdx.x;
  int c0 = split * COLS;

  // ---- stage hT slice: 64 dims x 512 B, 8 passes of 4 KB ----
#pragma unroll
  for (int p = 0; p < 8; ++p) {
    int flat = p * 4096 + tid * 16;    // byte offset within [64][512B]
    int srow = flat >> 9;              // dim
    int scol = (flat & 511) >> 1;      // short index within row
    bf16x8 v = *reinterpret_cast<const bf16x8*>(
        hT + (size_t)srow * N_NODES + c0 + scol);
    *reinterpret_cast<bf16x8*>(&hlds[srow * HROWB + scol]) = v;
  }
  if (tid < 64) {
    float4 tv4 = *reinterpret_cast<const float4*>(sdst + c0 + tid * 4);
    *reinterpret_cast<float4*>(&tlds[tid * 4]) = tv4;
  }
  __syncthreads();

  int wv = tid >> 6, lane = tid & 63;
  int lrow = lane & 15, kg = lane >> 4;
  int r0 = rb * 64 + wv * 16;
  int row = r0 + lrow;
  float s_i = ssrc[row];
  const int* adjr = adj + (size_t)row * N_NODES + c0 + kg * 8;

  f32x4 acc0 = {0.f, 0.f, 0.f, 0.f};
  f32x4 acc1 = acc0, acc2 = acc0, acc3 = acc0;
  float zacc = 0.f;

  // adj ring, depth 3 (tiles kt, kt+1, kt+2 in flight)
  int4 rgA[3], rgB[3];
#pragma unroll
  for (int i = 0; i < 3; ++i) {
    rgA[i] = *reinterpret_cast<const int4*>(adjr + i * 32);
    rgB[i] = *reinterpret_cast<const int4*>(adjr + i * 32 + 4);
  }

#pragma unroll
  for (int kt = 0; kt < NKT; ++kt) {
    int rs = kt % 3;                 // constant per unrolled instance
    int4 ca = rgA[rs], cb = rgB[rs];
    if (kt + 3 < NKT) {              // compile-time guard (full unroll)
      rgA[rs] = *reinterpret_cast<const int4*>(adjr + (kt + 3) * 32);
      rgB[rs] = *reinterpret_cast<const int4*>(adjr + (kt + 3) * 32 + 4);
    }
    int cbase = kt * 32 + kg * 8;
    float4 tA = *reinterpret_cast<const float4*>(&tlds[cbase]);
    float4 tB = *reinterpret_cast<const float4*>(&tlds[cbase + 4]);
    bf16x8 b0 = *reinterpret_cast<const bf16x8*>(&hlds[(lrow + 0) * HROWB + cbase]);
    bf16x8 b1 = *reinterpret_cast<const bf16x8*>(&hlds[(lrow + 16) * HROWB + cbase]);
    bf16x8 b2 = *reinterpret_cast<const bf16x8*>(&hlds[(lrow + 32) * HROWB + cbase]);
    bf16x8 b3 = *reinterpret_cast<const bf16x8*>(&hlds[(lrow + 48) * HROWB + cbase]);

    float tv[8] = {tA.x, tA.y, tA.z, tA.w, tB.x, tB.y, tB.z, tB.w};
    int av[8] = {ca.x, ca.y, ca.z, ca.w, cb.x, cb.y, cb.z, cb.w};
    bf16x8 af;
#pragma unroll
    for (int e = 0; e < 8; ++e) {
      float x = s_i + tv[e];                   // log2-domain score
      float lk = fmaxf(x, 0.2f * x);           // leakyrelu (alpha<1)
      float ev = __builtin_amdgcn_exp2f(lk);   // exp(leaky(s+t))
      float w = (av[e] != 0) ? ev : 0.f;       // mask
      zacc += w;
      af[e] = f2bf_fast(w);
    }
    acc0 = __builtin_amdgcn_mfma_f32_16x16x32_bf16(af, b0, acc0, 0, 0, 0);
    acc1 = __builtin_amdgcn_mfma_f32_16x16x32_bf16(af, b1, acc1, 0, 0, 0);
    acc2 = __builtin_amdgcn_mfma_f32_16x16x32_bf16(af, b2, acc2, 0, 0, 0);
    acc3 = __builtin_amdgcn_mfma_f32_16x16x32_bf16(af, b3, acc3, 0, 0, 0);
  }

  // Z: A-layout row = lane&15; sum over lanes {r, r+16, r+32, r+48}
  float z = zacc;
  z += __shfl_xor(z, 16);
  z += __shfl_xor(z, 32);
  if (lane < 16) pz[(size_t)split * N_NODES + r0 + lane] = z;

  // C/D layout: row = (lane>>4)*4 + reg, col = lane&15
  float* pa = pacc + (size_t)split * (N_NODES * NHID);
#pragma unroll
  for (int reg = 0; reg < 4; ++reg) {
    int orow = r0 + kg * 4 + reg;
    pa[(size_t)orow * NHID + 0 * 16 + lrow] = acc0[reg];
    pa[(size_t)orow * NHID + 1 * 16 + lrow] = acc1[reg];
    pa[(size_t)orow * NHID + 2 * 16 + lrow] = acc2[reg];
    pa[(size_t)orow * NHID + 3 * 16 + lrow] = acc3[reg];
  }
}

// Kernel 3: combine split partials and normalize.
__global__ __launch_bounds__(256) void gat_k3(
    const float* __restrict__ pacc, const float* __restrict__ pz,
    float* __restrict__ out) {
  int idx = blockIdx.x * 256 + threadIdx.x;
  int row = idx >> 6;
  float num = 0.f, den = 0.f;
#pragma unroll 8
  for (int s = 0; s < S_SPLIT; ++s) {
    num += pacc[(size_t)s * (N_NODES * NHID) + idx];
    den += pz[(size_t)s * N_NODES + row];
  }
  out[idx] = num / den;
}

extern "C" void kernel_launch(void* const* d_in, const int* in_sizes, int n_in,
                              void* d_out, int out_size, void* d_ws, size_t ws_size,
                              hipStream_t stream) {
  (void)in_sizes; (void)n_in; (void)out_size; (void)ws_size;
  const float* in = (const float*)d_in[0];
  const int* adj = (const int*)d_in[1];
  const float* W = (const float*)d_in[2];
  const float* a = (const float*)d_in[3];
  float* out = (float*)d_out;

  // ws: hT (1 MB) | ssrc (32K) | sdst (32K) | pz (1 MB) | pacc (64 MB)
  char* w = (char*)d_ws;
  short* hT = (short*)w;
  float* ssrc = (float*)(w + (1u << 20));
  float* sdst = ssrc + N_NODES;
  float* pz = sdst + N_NODES;
  float* pacc = pz + (size_t)S_SPLIT * N_NODES;

  gat_k1<<<N_NODES / 4, 256, 0, stream>>>(in, W, a, hT, ssrc, sdst);
  gat_k2<<<128 * S_SPLIT, 256, 0, stream>>>(adj, hT, ssrc, sdst, pacc, pz);
  gat_k3<<<(N_NODES * NHID) / 256, 256, 0, stream>>>(pacc, pz, out);
}

// Round 7
// 419.114 us; speedup vs baseline: 1.1634x; 1.0713x over previous
//
#include <hip/hip_runtime.h>
#include <hip/hip_bf16.h>

#define N_NODES 8192
#define EMB 256
#define NHID 64
#define LOG2E 1.44269504088896340736f
#define S_SPLIT 32
#define COLS 256       // cols per block = N_NODES / S_SPLIT
#define NKT 8          // K-tiles per block = COLS / 32
#define HROW 264       // padded LDS row stride (shorts) for hT tile
#define MROW 36        // padded LDS row stride (bytes) for adj bitmask

typedef __attribute__((ext_vector_type(8))) short bf16x8;
typedef __attribute__((ext_vector_type(4))) float f32x4;

static __device__ __forceinline__ short f2bf(float f) {
  __hip_bfloat16 h = __float2bfloat16(f);  // round-to-nearest-even
  return *reinterpret_cast<short*>(&h);
}

// fast bf16 round (half-up in magnitude) — used on nonnegative attention
// weights where ties-away vs ties-even rounding is noise.
static __device__ __forceinline__ short f2bf_fast(float f) {
  unsigned u = __builtin_bit_cast(unsigned, f);
  return (short)((u + 0x8000u) >> 16);
}

// Kernel 1: h = input @ W. One wave per row (lane = d).
// Writes hT[d][row] (bf16, transposed) + log2e-scaled s_src/s_dst.
__global__ __launch_bounds__(256) void gat_k1(
    const float* __restrict__ in, const float* __restrict__ W,
    const float* __restrict__ a, short* __restrict__ hT,
    float* __restrict__ ssrc, float* __restrict__ sdst) {
  int wave = threadIdx.x >> 6, lane = threadIdx.x & 63;
  int row = blockIdx.x * 4 + wave;
  int d = lane;
  const float4* in4 = reinterpret_cast<const float4*>(in + (size_t)row * EMB);
  float acc = 0.f;
#pragma unroll 4
  for (int k4 = 0; k4 < EMB / 4; ++k4) {
    float4 x = in4[k4];
    int k = k4 * 4;
    acc = fmaf(x.x, W[(k + 0) * NHID + d], acc);
    acc = fmaf(x.y, W[(k + 1) * NHID + d], acc);
    acc = fmaf(x.z, W[(k + 2) * NHID + d], acc);
    acc = fmaf(x.w, W[(k + 3) * NHID + d], acc);
  }
  hT[(size_t)d * N_NODES + row] = f2bf(acc);
  float p1 = acc * a[d];
  float p2 = acc * a[NHID + d];
#pragma unroll
  for (int off = 32; off > 0; off >>= 1) {
    p1 += __shfl_xor(p1, off);
    p2 += __shfl_xor(p2, off);
  }
  if (lane == 0) {
    ssrc[row] = p1 * LOG2E;
    sdst[row] = p2 * LOG2E;
  }
}

// Kernel 2: fused masked-exp + P@h via bf16 MFMA.
// Block = 64 rows x 256 cols. ALL data staged to LDS up front:
//   - hT slice (33 KB, padded)
//   - sdst slice (1 KB)
//   - adj tile as a bitmask (2.3 KB), staged with contiguous 1-KB-per-row
//     half-wave reads. The K-loop touches no global memory at all.
__global__ __launch_bounds__(256, 4) void gat_k2(
    const int* __restrict__ adj, const short* __restrict__ hT,
    const float* __restrict__ ssrc, const float* __restrict__ sdst,
    float* __restrict__ pacc, float* __restrict__ pz) {
  __shared__ short hlds[64 * HROW];          // 33792 B
  __shared__ unsigned char mlds[64 * MROW];  // 2304 B
  __shared__ float tlds[COLS];               // 1024 B

  int split = blockIdx.x >> 7;
  int rb = blockIdx.x & 127;
  int tid = threadIdx.x;
  int c0 = split * COLS;
  int wv = tid >> 6, lane = tid & 63;

  // ---- stage hT slice: 64 dims x 512 B ----
#pragma unroll
  for (int p = 0; p < 8; ++p) {
    int flat = p * 4096 + tid * 16;    // byte offset within [64][512B]
    int srow = flat >> 9;              // dim
    int scol = (flat & 511) >> 1;      // short index within row
    bf16x8 v = *reinterpret_cast<const bf16x8*>(
        hT + (size_t)srow * N_NODES + c0 + scol);
    *reinterpret_cast<bf16x8*>(&hlds[srow * HROW + scol]) = v;
  }
  if (tid < 64) {
    float4 t4 = *reinterpret_cast<const float4*>(sdst + c0 + tid * 4);
    *reinterpret_cast<float4*>(&tlds[tid * 4]) = t4;
  }
  // ---- stage adj tile -> bitmask; half-wave reads one full 1 KB row ----
  {
    int h = lane >> 5, sl = lane & 31;  // row-within-pair, sub-lane
#pragma unroll
    for (int p = 0; p < 8; ++p) {
      int r = wv * 16 + p * 2 + h;      // local row 0..63
      const int* ap = adj + (size_t)(rb * 64 + r) * N_NODES + c0 + sl * 8;
      int4 v0 = *reinterpret_cast<const int4*>(ap);
      int4 v1 = *reinterpret_cast<const int4*>(ap + 4);
      unsigned b = (unsigned)(v0.x != 0) | ((unsigned)(v0.y != 0) << 1) |
                   ((unsigned)(v0.z != 0) << 2) | ((unsigned)(v0.w != 0) << 3) |
                   ((unsigned)(v1.x != 0) << 4) | ((unsigned)(v1.y != 0) << 5) |
                   ((unsigned)(v1.z != 0) << 6) | ((unsigned)(v1.w != 0) << 7);
      mlds[r * MROW + sl] = (unsigned char)b;
    }
  }
  __syncthreads();

  int lrow = lane & 15, kg = lane >> 4;
  int r0 = rb * 64 + wv * 16;
  float s_i = ssrc[r0 + lrow];

  f32x4 acc0 = {0.f, 0.f, 0.f, 0.f};
  f32x4 acc1 = acc0, acc2 = acc0, acc3 = acc0;
  float zacc = 0.f;

#pragma unroll
  for (int kt = 0; kt < NKT; ++kt) {
    int cb = kt * 32 + kg * 8;
    // FIX (R6 bug): mask row is BLOCK-local (wv*16 + lrow), not wave-local.
    unsigned mb = mlds[(wv * 16 + lrow) * MROW + kt * 4 + kg];
    float4 tA = *reinterpret_cast<const float4*>(&tlds[cb]);
    float4 tB = *reinterpret_cast<const float4*>(&tlds[cb + 4]);
    bf16x8 b0 = *reinterpret_cast<const bf16x8*>(&hlds[(lrow + 0) * HROW + cb]);
    bf16x8 b1 = *reinterpret_cast<const bf16x8*>(&hlds[(lrow + 16) * HROW + cb]);
    bf16x8 b2 = *reinterpret_cast<const bf16x8*>(&hlds[(lrow + 32) * HROW + cb]);
    bf16x8 b3 = *reinterpret_cast<const bf16x8*>(&hlds[(lrow + 48) * HROW + cb]);

    float tv[8] = {tA.x, tA.y, tA.z, tA.w, tB.x, tB.y, tB.z, tB.w};
    bf16x8 af;
#pragma unroll
    for (int e = 0; e < 8; ++e) {
      float x = s_i + tv[e];                   // log2-domain score
      float lk = fmaxf(x, 0.2f * x);           // leakyrelu (alpha<1)
      float ev = __builtin_amdgcn_exp2f(lk);   // exp(leaky(s+t))
      float w = (mb & (1u << e)) ? ev : 0.f;   // mask
      zacc += w;
      af[e] = f2bf_fast(w);
    }
    acc0 = __builtin_amdgcn_mfma_f32_16x16x32_bf16(af, b0, acc0, 0, 0, 0);
    acc1 = __builtin_amdgcn_mfma_f32_16x16x32_bf16(af, b1, acc1, 0, 0, 0);
    acc2 = __builtin_amdgcn_mfma_f32_16x16x32_bf16(af, b2, acc2, 0, 0, 0);
    acc3 = __builtin_amdgcn_mfma_f32_16x16x32_bf16(af, b3, acc3, 0, 0, 0);
  }

  // Z: A-layout row = lane&15; sum over lanes {r, r+16, r+32, r+48}
  float z = zacc;
  z += __shfl_xor(z, 16);
  z += __shfl_xor(z, 32);
  if (lane < 16) pz[(size_t)split * N_NODES + r0 + lane] = z;

  // C/D layout: row = (lane>>4)*4 + reg, col = lane&15
  float* pa = pacc + (size_t)split * (N_NODES * NHID);
#pragma unroll
  for (int reg = 0; reg < 4; ++reg) {
    int orow = r0 + kg * 4 + reg;
    pa[(size_t)orow * NHID + 0 * 16 + lrow] = acc0[reg];
    pa[(size_t)orow * NHID + 1 * 16 + lrow] = acc1[reg];
    pa[(size_t)orow * NHID + 2 * 16 + lrow] = acc2[reg];
    pa[(size_t)orow * NHID + 3 * 16 + lrow] = acc3[reg];
  }
}

// Kernel 3: combine split partials and normalize (float4 per thread).
__global__ __launch_bounds__(256) void gat_k3(
    const float* __restrict__ pacc, const float* __restrict__ pz,
    float* __restrict__ out) {
  int t = blockIdx.x * 256 + threadIdx.x;  // indexes float4
  int row = t >> 4;                        // 16 float4 per row (NHID=64)
  float4 num = {0.f, 0.f, 0.f, 0.f};
  float den = 0.f;
#pragma unroll 8
  for (int s = 0; s < S_SPLIT; ++s) {
    float4 p = *reinterpret_cast<const float4*>(
        &pacc[(size_t)s * (N_NODES * NHID) + (size_t)t * 4]);
    num.x += p.x; num.y += p.y; num.z += p.z; num.w += p.w;
    den += pz[(size_t)s * N_NODES + row];
  }
  float r = 1.f / den;
  float4 o = {num.x * r, num.y * r, num.z * r, num.w * r};
  *reinterpret_cast<float4*>(&out[(size_t)t * 4]) = o;
}

extern "C" void kernel_launch(void* const* d_in, const int* in_sizes, int n_in,
                              void* d_out, int out_size, void* d_ws, size_t ws_size,
                              hipStream_t stream) {
  (void)in_sizes; (void)n_in; (void)out_size; (void)ws_size;
  const float* in = (const float*)d_in[0];
  const int* adj = (const int*)d_in[1];
  const float* W = (const float*)d_in[2];
  const float* a = (const float*)d_in[3];
  float* out = (float*)d_out;

  // ws: hT (1 MB) | ssrc (32K) | sdst (32K) | pz (1 MB) | pacc (64 MB)
  char* w = (char*)d_ws;
  short* hT = (short*)w;
  float* ssrc = (float*)(w + (1u << 20));
  float* sdst = ssrc + N_NODES;
  float* pz = sdst + N_NODES;
  float* pacc = pz + (size_t)S_SPLIT * N_NODES;

  gat_k1<<<N_NODES / 4, 256, 0, stream>>>(in, W, a, hT, ssrc, sdst);
  gat_k2<<<128 * S_SPLIT, 256, 0, stream>>>(adj, hT, ssrc, sdst, pacc, pz);
  gat_k3<<<(N_NODES * NHID) / (256 * 4), 256, 0, stream>>>(pacc, pz, out);
}